// Round 9
// baseline (311.390 us; speedup 1.0000x reference)
//
#include <hip/hip_runtime.h>
#include <math.h>

// Problem constants
#define Nq   1024
#define Dq   512
#define Hq   8
#define KH   3
#define DHq  64
#define NBH  32

typedef __attribute__((ext_vector_type(8))) __bf16 bf16x8;
typedef __attribute__((ext_vector_type(4))) float f32x4;

#define LDA 136   // LDS row stride (ushorts) for 128-wide K tiles
#define LDW 72    // LDS row stride (ushorts) for 64-wide tiles / Pn transpose

// ---------------- helpers ----------------

__device__ __forceinline__ unsigned short f2bf(float f) {  // RNE f32->bf16
    unsigned int u = __float_as_uint(f);
    u += 0x7FFFu + ((u >> 16) & 1u);
    return (unsigned short)(u >> 16);
}
__device__ __forceinline__ float bf2f(unsigned short b) {
    return __uint_as_float(((unsigned int)b) << 16);
}
// monotone 16-bit key for bf16 bit pattern
__device__ __forceinline__ unsigned key16(unsigned int b) {
    return (b & 0x8000u) ? (0xFFFFu & ~b) : (b | 0x8000u);
}
__device__ __forceinline__ uint2 pack4(float4 v) {
    return make_uint2((unsigned)f2bf(v.x) | ((unsigned)f2bf(v.y) << 16),
                      (unsigned)f2bf(v.z) | ((unsigned)f2bf(v.w) << 16));
}
__device__ __forceinline__ f32x4 fzero() { f32x4 z = {0.f, 0.f, 0.f, 0.f}; return z; }

// MFMA 16x16x32 bf16 fragment addressing (verified rounds 3-6):
//  A-frag: lane l holds A[row=l&15][k=(l>>4)*8+j]
//  B-frag: lane l holds B[k=(l>>4)*8+j][col=l&15]  (B^T row-major)
//  C/D:    reg r -> C[row=(l>>4)*4+r][col=l&15]
// Lesson (r5): fragment reads MUST come from LDS; direct-global fragment loads
// are 16B/lane at 2KB lane stride = uncoalesced, ~2x slower kernels.

// ---------------- kernels ----------------

// by<32: X f32 -> Xn bf16 [bh][1024][64] and Xt bf16 [bh][64][1024]
// by==32: prep W_filt -> WtB bf16 [h*4+k][e][d], W_proj -> WpB bf16 [j][d]
__global__ __launch_bounds__(256) void xcast_kernel(const float* __restrict__ X,
                                                    unsigned short* __restrict__ Xn,
                                                    unsigned short* __restrict__ Xt,
                                                    const float* __restrict__ Wf,
                                                    const float* __restrict__ Wp,
                                                    unsigned short* __restrict__ WtB,
                                                    unsigned short* __restrict__ WpB) {
    int tid = threadIdx.x;
    if (blockIdx.y == 32) {  // weight prep
        int bx = blockIdx.x;
#pragma unroll
        for (int mm = 0; mm < 2; ++mm) {
            int m = bx * 2 + mm;
            for (int u = tid; u < 4096; u += 256) {
                int d = u >> 6, e = u & 63;
                WtB[m * 4096 + e * 64 + d] = f2bf(Wf[m * 4096 + d * 64 + e]);
            }
        }
        for (int u = tid; u < 32 * 128; u += 256) {
            int r = bx * 32 + (u >> 7), c4 = (u & 127) << 2;
            float4 v = *(const float4*)&Wp[(size_t)r * Dq + c4];
            *(uint2*)&WpB[(size_t)r * Dq + c4] = pack4(v);
        }
        return;
    }
    __shared__ float T[64][68];
    int bh = blockIdx.y, b = bh >> 3, h = bh & 7;
    int n0 = blockIdx.x << 6;
    const float* Xg = X + ((size_t)b * Nq + n0) * Dq + h * DHq;
#pragma unroll
    for (int u = 0; u < 4; ++u) {
        int idx = tid + (u << 8);
        int r = idx >> 4, c4 = (idx & 15) << 2;
        float4 v = *(const float4*)&Xg[(size_t)r * Dq + c4];
        *(uint2*)&Xn[((size_t)bh * Nq + n0 + r) * DHq + c4] = pack4(v);
        T[c4 + 0][r] = v.x; T[c4 + 1][r] = v.y; T[c4 + 2][r] = v.z; T[c4 + 3][r] = v.w;
    }
    __syncthreads();
#pragma unroll
    for (int u = 0; u < 4; ++u) {
        int idx = tid + (u << 8);
        int d = idx >> 4, n4 = (idx & 15) << 2;
        float4 v = make_float4(T[d][n4], T[d][n4 + 1], T[d][n4 + 2], T[d][n4 + 3]);
        *(uint2*)&Xt[((size_t)bh * DHq + d) * Nq + n0 + n4] = pack4(v);
    }
}

// S[bh,i,j] = dot(Xh[i],Xh[j]) / (8*clip(tau)), bf16 MFMA.
// Epilogue stages C through LDS (stride 68: 4-row groups 8 banks apart,
// conflict-free) -> 2 coalesced uint4 stores/thread.
__global__ __launch_bounds__(256) void score_mfma(const unsigned short* __restrict__ Xn,
                                                  const float* __restrict__ temperature,
                                                  unsigned short* __restrict__ Sbf) {
    __shared__ unsigned short Xi[64 * LDW], Xj[64 * LDW];
    __shared__ unsigned short Cst[64 * 68];
    int tid = threadIdx.x, lane = tid & 63, w = tid >> 6;
    int bh = blockIdx.z, i0 = blockIdx.y << 6, j0 = blockIdx.x << 6;
    const unsigned short* Xb = Xn + (size_t)bh * Nq * DHq;
    {
        int row = tid >> 3, o = (tid & 7) << 3;
#pragma unroll
        for (int u = 0; u < 2; ++u) {
            int r = row + (u << 5);
            *(uint4*)&Xi[r * LDW + o] = *(const uint4*)&Xb[(size_t)(i0 + r) * DHq + o];
            *(uint4*)&Xj[r * LDW + o] = *(const uint4*)&Xb[(size_t)(j0 + r) * DHq + o];
        }
    }
    __syncthreads();
    f32x4 acc[4] = {fzero(), fzero(), fzero(), fzero()};
    int brow = lane & 15, g = lane >> 4, ko = g << 3;
    const unsigned short* Afr = &Xi[((w << 4) + brow) * LDW + ko];
#pragma unroll
    for (int ks = 0; ks < 2; ++ks) {
        bf16x8 af = *(const bf16x8*)(Afr + (ks << 5));
#pragma unroll
        for (int nt = 0; nt < 4; ++nt) {
            bf16x8 bfv = *(const bf16x8*)&Xj[((nt << 4) + brow) * LDW + (ks << 5) + ko];
            acc[nt] = __builtin_amdgcn_mfma_f32_16x16x32_bf16(af, bfv, acc[nt], 0, 0, 0);
        }
    }
    float tau = fminf(fmaxf(temperature[bh & 7], 0.1f), 5.0f);
    float inv = 1.0f / (8.0f * tau);
    int nrow = (w << 4) + (g << 2);
#pragma unroll
    for (int nt = 0; nt < 4; ++nt)
#pragma unroll
        for (int r = 0; r < 4; ++r)
            Cst[(nrow + r) * 68 + (nt << 4) + brow] = f2bf(acc[nt][r] * inv);
    __syncthreads();
    {
        int rr = tid >> 2, c16 = (tid & 3) << 4;
        unsigned short* Sp = Sbf + ((size_t)bh * Nq + i0 + rr) * Nq + j0 + c16;
        *(uint4*)Sp       = *(const uint4*)&Cst[rr * 68 + c16];
        *(uint4*)(Sp + 8) = *(const uint4*)&Cst[rr * 68 + c16 + 8];
    }
}

// One row per wave: exact k-th-largest via register binary search on 16-bit
// bf16 keys (v_cmp/ballot counting), then masked softmax. bf16 in/out in place.
// maxk skip + early exit: if cnt(>=t)==kv exactly, tk = min{key>=t} (one
// masked min-reduce replaces all remaining bit iterations).
__global__ __launch_bounds__(256) void topk_softmax_kernel(unsigned short* __restrict__ Sbf,
                                                           const int* __restrict__ layer_idx,
                                                           const int* __restrict__ Lptr) {
    int tid = threadIdx.x;
    int w = tid >> 6, lane = tid & 63;
    unsigned short* Srow = Sbf + ((size_t)blockIdx.x * 4 + w) * Nq;
    uint4 q0 = ((const uint4*)Srow)[lane * 2];
    uint4 q1 = ((const uint4*)Srow)[lane * 2 + 1];
    float v[16]; unsigned int k16[16];
    {
        unsigned int ww[8] = {q0.x, q0.y, q0.z, q0.w, q1.x, q1.y, q1.z, q1.w};
#pragma unroll
        for (int i = 0; i < 8; ++i) {
            unsigned lo16 = ww[i] & 0xFFFFu, hi16 = ww[i] >> 16;
            v[2 * i]       = __uint_as_float(lo16 << 16);
            v[2 * i + 1]   = __uint_as_float(hi16 << 16);
            k16[2 * i]     = key16(lo16);
            k16[2 * i + 1] = key16(hi16);
        }
    }

    double sp = 0.8 + (0.2 - 0.8) * exp(-3.0 * (double)layer_idx[0] / (double)Lptr[0]);
    int kv = (int)((1.0 - sp) * (double)Nq);
    if (kv < 1) kv = 1;

    // row max first (wave-uniform) — also bounds the key search
    float m = v[0];
#pragma unroll
    for (int i = 1; i < 16; ++i) m = fmaxf(m, v[i]);
#pragma unroll
    for (int off = 32; off; off >>= 1) m = fmaxf(m, __shfl_xor(m, off));
    unsigned int maxk = key16(__float_as_uint(m) >> 16);

    unsigned int tk = 0;
    if (kv < Nq) {
        unsigned int lo = 0;
        bool done = false;
#pragma unroll
        for (int bit = 15; bit >= 0; --bit) {
            if (done) continue;
            unsigned int t = lo | (1u << bit);
            if (t > maxk) continue;  // cnt would be 0 < kv
            int cnt = 0;
#pragma unroll
            for (int i = 0; i < 16; ++i)
                cnt += (int)__popcll(__ballot(k16[i] >= t));
            if (cnt >= kv) {
                lo = t;
                if (cnt == kv) {  // top-kv set == {key>=t}; tk = its min
                    unsigned int mn = 0xFFFFu;
#pragma unroll
                    for (int i = 0; i < 16; ++i)
                        mn = min(mn, (k16[i] >= t) ? k16[i] : 0xFFFFu);
#pragma unroll
                    for (int off = 32; off; off >>= 1)
                        mn = min(mn, (unsigned)__shfl_xor((int)mn, off));
                    lo = mn;
                    done = true;
                }
            }
        }
        tk = lo;
    }

    float sum = 0.f;
#pragma unroll
    for (int i = 0; i < 16; ++i) {
        float e = (k16[i] >= tk) ? __expf(v[i] - m) : 0.0f;
        v[i] = e; sum += e;
    }
#pragma unroll
    for (int off = 32; off; off >>= 1) sum += __shfl_xor(sum, off);
    float is = 1.0f / sum;
    unsigned int ow[8];
#pragma unroll
    for (int i = 0; i < 8; ++i)
        ow[i] = (unsigned)f2bf(v[2 * i] * is) | ((unsigned)f2bf(v[2 * i + 1] * is) << 16);
    ((uint4*)Srow)[lane * 2]     = make_uint4(ow[0], ow[1], ow[2], ow[3]);
    ((uint4*)Srow)[lane * 2 + 1] = make_uint4(ow[4], ow[5], ow[6], ow[7]);
}

// Fused hop: Pn = A @ Pprev (LDS-staged, double-buffered, one barrier/K-step,
// 2-deep register prefetch: loads for kt+2 issued at kt, consumed at kt+1 —
// a full iteration of latency cover instead of ~80 cycles);
// [writeP: store Pn^T bf16]; filter GEMM from pre-transposed bf16 weights:
//   khop==1: Hacc = a0*(Xh@W0) + a1*(Pn@W1)   (bf16 store, init; hop-0 fused)
//   else:    Hacc += a_k*(Pn@Wk)              (bf16 RMW)
__global__ __launch_bounds__(256) void apf_mfma(const unsigned short* __restrict__ Abf,
                                                const unsigned short* __restrict__ Ptin,
                                                unsigned short* __restrict__ Ptout, int writeP,
                                                const unsigned short* __restrict__ Xn,
                                                const unsigned short* __restrict__ WtB,
                                                const float* __restrict__ alpha,
                                                unsigned short* __restrict__ HaccB, int khop) {
    __shared__ unsigned short A_lds[2][64 * LDA];
    __shared__ unsigned short P_lds[2][64 * LDA];
    int tid = threadIdx.x, lane = tid & 63, w = tid >> 6;
    int bh = blockIdx.y, b = bh >> 3, h = bh & 7;
    int i0 = blockIdx.x << 6;
    const unsigned short* Ag = Abf + ((size_t)bh * Nq + i0) * Nq;   // [n][j]
    const unsigned short* Pg = Ptin + (size_t)bh * DHq * Nq;        // [d][n]
    int r0 = tid >> 4, oo = (tid & 15) << 3;

    uint4 ra[2][4], rp[2][4];
    // prologue: s0 -> set0 -> lds[0]; s1 -> set1 (left in flight)
#pragma unroll
    for (int u = 0; u < 4; ++u) {
        ra[0][u] = *(const uint4*)&Ag[(size_t)(r0 + (u << 4)) * Nq + oo];
        rp[0][u] = *(const uint4*)&Pg[(size_t)(r0 + (u << 4)) * Nq + oo];
    }
#pragma unroll
    for (int u = 0; u < 4; ++u) {
        *(uint4*)&A_lds[0][(r0 + (u << 4)) * LDA + oo] = ra[0][u];
        *(uint4*)&P_lds[0][(r0 + (u << 4)) * LDA + oo] = rp[0][u];
    }
#pragma unroll
    for (int u = 0; u < 4; ++u) {
        ra[1][u] = *(const uint4*)&Ag[(size_t)(r0 + (u << 4)) * Nq + 128 + oo];
        rp[1][u] = *(const uint4*)&Pg[(size_t)(r0 + (u << 4)) * Nq + 128 + oo];
    }
    __syncthreads();

    f32x4 acc[4] = {fzero(), fzero(), fzero(), fzero()};
    int brow = lane & 15, g = lane >> 4, ko = g << 3;
    int cur = 0;

#pragma unroll
    for (int kt = 0; kt < 8; ++kt) {
        const int si = kt & 1;      // set to issue into (its data already in LDS)
        const int sw = si ^ 1;      // set to write to LDS (loaded one iter ago)
        if (kt < 6) {
            int j = (kt + 2) << 7;
#pragma unroll
            for (int u = 0; u < 4; ++u) {
                ra[si][u] = *(const uint4*)&Ag[(size_t)(r0 + (u << 4)) * Nq + j + oo];
                rp[si][u] = *(const uint4*)&Pg[(size_t)(r0 + (u << 4)) * Nq + j + oo];
            }
        }
        const unsigned short* Afr = &A_lds[cur][((w << 4) + brow) * LDA + ko];
#pragma unroll
        for (int ks = 0; ks < 4; ++ks) {
            bf16x8 af = *(const bf16x8*)(Afr + (ks << 5));
#pragma unroll
            for (int nt = 0; nt < 4; ++nt) {
                bf16x8 bfv = *(const bf16x8*)&P_lds[cur][((nt << 4) + brow) * LDA + (ks << 5) + ko];
                acc[nt] = __builtin_amdgcn_mfma_f32_16x16x32_bf16(af, bfv, acc[nt], 0, 0, 0);
            }
        }
        if (kt < 7) {  // write other buffer: no WAR hazard, one barrier
#pragma unroll
            for (int u = 0; u < 4; ++u) {
                *(uint4*)&A_lds[cur ^ 1][(r0 + (u << 4)) * LDA + oo] = ra[sw][u];
                *(uint4*)&P_lds[cur ^ 1][(r0 + (u << 4)) * LDA + oo] = rp[sw][u];
            }
        }
        __syncthreads();
        cur ^= 1;
    }

    // acc: Pn[row=(w<<4)+(g<<2)+r][col=(nt<<4)+brow]
    int nrow = (w << 4) + (g << 2);
    int dcol = brow;
    if (writeP) {
#pragma unroll
        for (int nt = 0; nt < 4; ++nt) {
            uint2 pk = make_uint2(
                (unsigned)f2bf(acc[nt][0]) | ((unsigned)f2bf(acc[nt][1]) << 16),
                (unsigned)f2bf(acc[nt][2]) | ((unsigned)f2bf(acc[nt][3]) << 16));
            *(uint2*)&Ptout[(size_t)bh * DHq * Nq + (size_t)((nt << 4) + dcol) * Nq + i0 + nrow] = pk;
        }
    }
    // Pn -> A-frag layout [n][d]; wave-private 16-row slices, reuse A_lds[0].
    // (Last K-step read A_lds[1]; slices are disjoint per wave -> no barrier.)
    unsigned short* PnL = &A_lds[0][0];
#pragma unroll
    for (int nt = 0; nt < 4; ++nt)
#pragma unroll
        for (int r = 0; r < 4; ++r)
            PnL[(nrow + r) * LDW + (nt << 4) + dcol] = f2bf(acc[nt][r]);

    // filter GEMM(s), K=64; W fragments direct from pre-transposed bf16 (tiny, L2-hot)
    const unsigned short* Wk = WtB + (size_t)(h * (KH + 1) + khop) * DHq * DHq;  // [e][d]
    f32x4 hacc[4] = {fzero(), fzero(), fzero(), fzero()};
    f32x4 hacc0[4] = {fzero(), fzero(), fzero(), fzero()};
#pragma unroll
    for (int ks = 0; ks < 2; ++ks) {
        bf16x8 pf = *(const bf16x8*)&PnL[((w << 4) + brow) * LDW + (ks << 5) + ko];
#pragma unroll
        for (int nt = 0; nt < 4; ++nt) {
            bf16x8 wf = *(const bf16x8*)&Wk[(size_t)((nt << 4) + brow) * DHq + (ks << 5) + ko];
            hacc[nt] = __builtin_amdgcn_mfma_f32_16x16x32_bf16(pf, wf, hacc[nt], 0, 0, 0);
        }
    }
    if (khop == 1) {  // fused hop-0: Xh @ W0
        const unsigned short* W0 = WtB + (size_t)(h * (KH + 1)) * DHq * DHq;
        const unsigned short* Xb = Xn + ((size_t)bh * Nq + i0) * DHq;
        int arow = (w << 4) + brow;
#pragma unroll
        for (int ks = 0; ks < 2; ++ks) {
            bf16x8 xf = *(const bf16x8*)&Xb[(size_t)arow * DHq + (ks << 5) + ko];
#pragma unroll
            for (int nt = 0; nt < 4; ++nt) {
                bf16x8 wf = *(const bf16x8*)&W0[(size_t)((nt << 4) + brow) * DHq + (ks << 5) + ko];
                hacc0[nt] = __builtin_amdgcn_mfma_f32_16x16x32_bf16(xf, wf, hacc0[nt], 0, 0, 0);
            }
        }
    }
    float av = alpha[h * (KH + 1) + khop];
    unsigned short* Ho = HaccB + ((size_t)b * Nq + i0 + nrow) * Dq + h * DHq;
    if (khop == 1) {
        float a0 = alpha[h * (KH + 1)];
#pragma unroll
        for (int nt = 0; nt < 4; ++nt)
#pragma unroll
            for (int r = 0; r < 4; ++r)
                Ho[(size_t)r * Dq + (nt << 4) + brow] = f2bf(a0 * hacc0[nt][r] + av * hacc[nt][r]);
    } else {
#pragma unroll
        for (int nt = 0; nt < 4; ++nt)
#pragma unroll
            for (int r = 0; r < 4; ++r) {
                unsigned short* p = Ho + (size_t)r * Dq + (nt << 4) + brow;
                *p = f2bf(bf2f(*p) + av * hacc[nt][r]);
            }
    }
}

// out = Hacc @ W_proj^T + b  (bf16 staged through LDS, f32 out)
__global__ __launch_bounds__(256) void proj_mfma(const unsigned short* __restrict__ HaccB,
                                                 const unsigned short* __restrict__ WpB,
                                                 const float* __restrict__ bp,
                                                 float* __restrict__ out) {
    __shared__ unsigned short Hl[64 * LDA], Wl[64 * LDA];
    int tid = threadIdx.x, lane = tid & 63, w = tid >> 6;
    int i0 = blockIdx.y << 6, j0 = blockIdx.x << 6;
    int brow = lane & 15, ko = (lane >> 4) << 3;
    f32x4 acc[4] = {fzero(), fzero(), fzero(), fzero()};
    for (int kt = 0; kt < 4; ++kt) {
#pragma unroll
        for (int u = 0; u < 4; ++u) {
            int idx = tid + (u << 8);
            int r = idx >> 4, c8 = (idx & 15) << 3;
            *(uint4*)&Hl[r * LDA + c8] = *(const uint4*)&HaccB[(size_t)(i0 + r) * Dq + (kt << 7) + c8];
            *(uint4*)&Wl[r * LDA + c8] = *(const uint4*)&WpB[(size_t)(j0 + r) * Dq + (kt << 7) + c8];
        }
        __syncthreads();
        const unsigned short* Afr = &Hl[((w << 4) + brow) * LDA + ko];
#pragma unroll
        for (int ks = 0; ks < 4; ++ks) {
            bf16x8 af = *(const bf16x8*)(Afr + (ks << 5));
#pragma unroll
            for (int nt = 0; nt < 4; ++nt) {
                bf16x8 bfv = *(const bf16x8*)&Wl[((nt << 4) + brow) * LDA + (ks << 5) + ko];
                acc[nt] = __builtin_amdgcn_mfma_f32_16x16x32_bf16(af, bfv, acc[nt], 0, 0, 0);
            }
        }
        __syncthreads();
    }
    int nrow = (w << 4) + ((lane >> 4) << 2);
#pragma unroll
    for (int nt = 0; nt < 4; ++nt) {
        float bb = bp[j0 + (nt << 4) + brow];
#pragma unroll
        for (int r = 0; r < 4; ++r)
            out[(size_t)(i0 + nrow + r) * Dq + j0 + (nt << 4) + brow] = acc[nt][r] + bb;
    }
}

// ---------------- launch ----------------

extern "C" void kernel_launch(void* const* d_in, const int* in_sizes, int n_in,
                              void* d_out, int out_size, void* d_ws, size_t ws_size,
                              hipStream_t stream) {
    (void)in_sizes; (void)n_in; (void)out_size; (void)ws_size;
    const float* X           = (const float*)d_in[0];
    const float* temperature = (const float*)d_in[1];
    const float* W_filt      = (const float*)d_in[2];
    const float* alpha       = (const float*)d_in[3];
    const float* W_proj      = (const float*)d_in[4];
    const float* b_proj      = (const float*)d_in[5];
    const int*   layer_idx   = (const int*)d_in[6];
    const int*   Lp          = (const int*)d_in[7];
    float* out = (float*)d_out;

    unsigned short* Abf  = (unsigned short*)d_ws;                   // S/A in place, 64 MiB
    unsigned short* Xn   = Abf  + (size_t)NBH * Nq * Nq;            // [32][1024][64]
    unsigned short* Xt   = Xn   + (size_t)NBH * Nq * DHq;           // [32][64][1024]
    unsigned short* Pt1  = Xt   + (size_t)NBH * DHq * Nq;           // [32][64][1024]
    unsigned short* Pt2  = Pt1  + (size_t)NBH * DHq * Nq;           // [32][64][1024]
    unsigned short* Hacc = Pt2  + (size_t)NBH * DHq * Nq;           // [4][1024][512] bf16
    unsigned short* WtB  = Hacc + (size_t)4 * Nq * Dq;              // [32][64][64]
    unsigned short* WpB  = WtB  + (size_t)NBH * DHq * DHq;          // [512][512]

    dim3 blk(256);
    xcast_kernel<<<dim3(16, 33), blk, 0, stream>>>(X, Xn, Xt, W_filt, W_proj, WtB, WpB);
    score_mfma<<<dim3(16, 16, 32), blk, 0, stream>>>(Xn, temperature, Abf);
    topk_softmax_kernel<<<dim3(NBH * Nq / 4), blk, 0, stream>>>(Abf, layer_idx, Lp);

    // hop 1 (+ fused hop 0): Pn = A @ Xh (Pprev^T = Xt); write Pt1
    apf_mfma<<<dim3(16, 32), blk, 0, stream>>>(Abf, Xt, Pt1, 1, Xn, WtB, alpha, Hacc, 1);
    // hop 2
    apf_mfma<<<dim3(16, 32), blk, 0, stream>>>(Abf, Pt1, Pt2, 1, Xn, WtB, alpha, Hacc, 2);
    // hop 3 (no P write)
    apf_mfma<<<dim3(16, 32), blk, 0, stream>>>(Abf, Pt2, nullptr, 0, Xn, WtB, alpha, Hacc, 3);

    proj_mfma<<<dim3(8, 64), blk, 0, stream>>>(Hacc, WpB, b_proj, out);
}

// Round 11
// 216.388 us; speedup vs baseline: 1.4390x; 1.4390x over previous
//
#include <hip/hip_runtime.h>
#include <math.h>

// Problem constants
#define Nq   1024
#define Dq   512
#define Hq   8
#define KH   3
#define DHq  64
#define NBH  32

typedef __attribute__((ext_vector_type(8))) __bf16 bf16x8;
typedef __attribute__((ext_vector_type(4))) float f32x4;

#define LDA 136   // LDS row stride (ushorts) for 128-wide K tiles
#define LDW 72    // LDS row stride (ushorts) for Pn transpose

// ---------------- helpers ----------------

__device__ __forceinline__ unsigned short f2bf(float f) {  // RNE f32->bf16
    unsigned int u = __float_as_uint(f);
    u += 0x7FFFu + ((u >> 16) & 1u);
    return (unsigned short)(u >> 16);
}
__device__ __forceinline__ float bf2f(unsigned short b) {
    return __uint_as_float(((unsigned int)b) << 16);
}
// monotone 16-bit key for bf16 bit pattern
__device__ __forceinline__ unsigned key16(unsigned int b) {
    return (b & 0x8000u) ? (0xFFFFu & ~b) : (b | 0x8000u);
}
__device__ __forceinline__ uint2 pack4(float4 v) {
    return make_uint2((unsigned)f2bf(v.x) | ((unsigned)f2bf(v.y) << 16),
                      (unsigned)f2bf(v.z) | ((unsigned)f2bf(v.w) << 16));
}
__device__ __forceinline__ f32x4 fzero() { f32x4 z = {0.f, 0.f, 0.f, 0.f}; return z; }

// MFMA 16x16x32 bf16 fragment addressing (verified rounds 3-6):
//  A-frag: lane l holds A[row=l&15][k=(l>>4)*8+j]
//  B-frag: lane l holds B[k=(l>>4)*8+j][col=l&15]  (B^T row-major)
//  C/D:    reg r -> C[row=(l>>4)*4+r][col=l&15]
// Lesson (r5): fragment reads MUST come from LDS; direct-global fragment loads
// are 16B/lane at 2KB lane stride = uncoalesced, ~2x slower kernels.
// Lesson (r9): >1-deep register prefetch (16 uint4 staging regs) spills to
// scratch (WRITE_SIZE 8MB->134MB, MfmaUtil 3%). Keep staging regs <= 8 uint4.
// Lesson (r10): do NOT alias one __shared__ array through a second pointer
// with a different stride and rely on intra-wave DS ordering — post-timing
// divergence. PnL is now a dedicated array with a barrier before reads.

// ---------------- kernels ----------------

// by<32: X f32 -> Xn bf16 [bh][1024][64] and Xt bf16 [bh][64][1024]
// by==32: prep W_filt -> WtB bf16 [h*4+k][e][d], W_proj -> WpB bf16 [j][d]
__global__ __launch_bounds__(256) void xcast_kernel(const float* __restrict__ X,
                                                    unsigned short* __restrict__ Xn,
                                                    unsigned short* __restrict__ Xt,
                                                    const float* __restrict__ Wf,
                                                    const float* __restrict__ Wp,
                                                    unsigned short* __restrict__ WtB,
                                                    unsigned short* __restrict__ WpB) {
    int tid = threadIdx.x;
    if (blockIdx.y == 32) {  // weight prep
        int bx = blockIdx.x;
#pragma unroll
        for (int mm = 0; mm < 2; ++mm) {
            int m = bx * 2 + mm;
            for (int u = tid; u < 4096; u += 256) {
                int d = u >> 6, e = u & 63;
                WtB[m * 4096 + e * 64 + d] = f2bf(Wf[m * 4096 + d * 64 + e]);
            }
        }
        for (int u = tid; u < 32 * 128; u += 256) {
            int r = bx * 32 + (u >> 7), c4 = (u & 127) << 2;
            float4 v = *(const float4*)&Wp[(size_t)r * Dq + c4];
            *(uint2*)&WpB[(size_t)r * Dq + c4] = pack4(v);
        }
        return;
    }
    __shared__ float T[64][68];
    int bh = blockIdx.y, b = bh >> 3, h = bh & 7;
    int n0 = blockIdx.x << 6;
    const float* Xg = X + ((size_t)b * Nq + n0) * Dq + h * DHq;
#pragma unroll
    for (int u = 0; u < 4; ++u) {
        int idx = tid + (u << 8);
        int r = idx >> 4, c4 = (idx & 15) << 2;
        float4 v = *(const float4*)&Xg[(size_t)r * Dq + c4];
        *(uint2*)&Xn[((size_t)bh * Nq + n0 + r) * DHq + c4] = pack4(v);
        T[c4 + 0][r] = v.x; T[c4 + 1][r] = v.y; T[c4 + 2][r] = v.z; T[c4 + 3][r] = v.w;
    }
    __syncthreads();
#pragma unroll
    for (int u = 0; u < 4; ++u) {
        int idx = tid + (u << 8);
        int d = idx >> 4, n4 = (idx & 15) << 2;
        float4 v = make_float4(T[d][n4], T[d][n4 + 1], T[d][n4 + 2], T[d][n4 + 3]);
        *(uint2*)&Xt[((size_t)bh * DHq + d) * Nq + n0 + n4] = pack4(v);
    }
}

// S[bh,i,j] = dot(Xh[i],Xh[j]) / (8*clip(tau)), bf16 MFMA.
// Epilogue stages C through LDS -> 2 coalesced uint4 stores/thread.
__global__ __launch_bounds__(256) void score_mfma(const unsigned short* __restrict__ Xn,
                                                  const float* __restrict__ temperature,
                                                  unsigned short* __restrict__ Sbf) {
    __shared__ unsigned short Xi[64 * LDW], Xj[64 * LDW];
    __shared__ unsigned short Cst[64 * 68];
    int tid = threadIdx.x, lane = tid & 63, w = tid >> 6;
    int bh = blockIdx.z, i0 = blockIdx.y << 6, j0 = blockIdx.x << 6;
    const unsigned short* Xb = Xn + (size_t)bh * Nq * DHq;
    {
        int row = tid >> 3, o = (tid & 7) << 3;
#pragma unroll
        for (int u = 0; u < 2; ++u) {
            int r = row + (u << 5);
            *(uint4*)&Xi[r * LDW + o] = *(const uint4*)&Xb[(size_t)(i0 + r) * DHq + o];
            *(uint4*)&Xj[r * LDW + o] = *(const uint4*)&Xb[(size_t)(j0 + r) * DHq + o];
        }
    }
    __syncthreads();
    f32x4 acc[4] = {fzero(), fzero(), fzero(), fzero()};
    int brow = lane & 15, g = lane >> 4, ko = g << 3;
    const unsigned short* Afr = &Xi[((w << 4) + brow) * LDW + ko];
#pragma unroll
    for (int ks = 0; ks < 2; ++ks) {
        bf16x8 af = *(const bf16x8*)(Afr + (ks << 5));
#pragma unroll
        for (int nt = 0; nt < 4; ++nt) {
            bf16x8 bfv = *(const bf16x8*)&Xj[((nt << 4) + brow) * LDW + (ks << 5) + ko];
            acc[nt] = __builtin_amdgcn_mfma_f32_16x16x32_bf16(af, bfv, acc[nt], 0, 0, 0);
        }
    }
    float tau = fminf(fmaxf(temperature[bh & 7], 0.1f), 5.0f);
    float inv = 1.0f / (8.0f * tau);
    int nrow = (w << 4) + (g << 2);
#pragma unroll
    for (int nt = 0; nt < 4; ++nt)
#pragma unroll
        for (int r = 0; r < 4; ++r)
            Cst[(nrow + r) * 68 + (nt << 4) + brow] = f2bf(acc[nt][r] * inv);
    __syncthreads();
    {
        int rr = tid >> 2, c16 = (tid & 3) << 4;
        unsigned short* Sp = Sbf + ((size_t)bh * Nq + i0 + rr) * Nq + j0 + c16;
        *(uint4*)Sp       = *(const uint4*)&Cst[rr * 68 + c16];
        *(uint4*)(Sp + 8) = *(const uint4*)&Cst[rr * 68 + c16 + 8];
    }
}

// One row per wave: exact k-th-largest via register binary search on 16-bit
// bf16 keys (v_cmp/ballot counting), then masked softmax. bf16 in/out in place.
// maxk skip + early exit (cnt==kv -> min-reduce).
__global__ __launch_bounds__(256) void topk_softmax_kernel(unsigned short* __restrict__ Sbf,
                                                           const int* __restrict__ layer_idx,
                                                           const int* __restrict__ Lptr) {
    int tid = threadIdx.x;
    int w = tid >> 6, lane = tid & 63;
    unsigned short* Srow = Sbf + ((size_t)blockIdx.x * 4 + w) * Nq;
    uint4 q0 = ((const uint4*)Srow)[lane * 2];
    uint4 q1 = ((const uint4*)Srow)[lane * 2 + 1];
    float v[16]; unsigned int k16[16];
    {
        unsigned int ww[8] = {q0.x, q0.y, q0.z, q0.w, q1.x, q1.y, q1.z, q1.w};
#pragma unroll
        for (int i = 0; i < 8; ++i) {
            unsigned lo16 = ww[i] & 0xFFFFu, hi16 = ww[i] >> 16;
            v[2 * i]       = __uint_as_float(lo16 << 16);
            v[2 * i + 1]   = __uint_as_float(hi16 << 16);
            k16[2 * i]     = key16(lo16);
            k16[2 * i + 1] = key16(hi16);
        }
    }

    double sp = 0.8 + (0.2 - 0.8) * exp(-3.0 * (double)layer_idx[0] / (double)Lptr[0]);
    int kv = (int)((1.0 - sp) * (double)Nq);
    if (kv < 1) kv = 1;

    // row max first (wave-uniform) — also bounds the key search
    float m = v[0];
#pragma unroll
    for (int i = 1; i < 16; ++i) m = fmaxf(m, v[i]);
#pragma unroll
    for (int off = 32; off; off >>= 1) m = fmaxf(m, __shfl_xor(m, off));
    unsigned int maxk = key16(__float_as_uint(m) >> 16);

    unsigned int tk = 0;
    if (kv < Nq) {
        unsigned int lo = 0;
        bool done = false;
#pragma unroll
        for (int bit = 15; bit >= 0; --bit) {
            if (done) continue;
            unsigned int t = lo | (1u << bit);
            if (t > maxk) continue;  // cnt would be 0 < kv
            int cnt = 0;
#pragma unroll
            for (int i = 0; i < 16; ++i)
                cnt += (int)__popcll(__ballot(k16[i] >= t));
            if (cnt >= kv) {
                lo = t;
                if (cnt == kv) {  // top-kv set == {key>=t}; tk = its min
                    unsigned int mn = 0xFFFFu;
#pragma unroll
                    for (int i = 0; i < 16; ++i)
                        mn = min(mn, (k16[i] >= t) ? k16[i] : 0xFFFFu);
#pragma unroll
                    for (int off = 32; off; off >>= 1)
                        mn = min(mn, (unsigned)__shfl_xor((int)mn, off));
                    lo = mn;
                    done = true;
                }
            }
        }
        tk = lo;
    }

    float sum = 0.f;
#pragma unroll
    for (int i = 0; i < 16; ++i) {
        float e = (k16[i] >= tk) ? __expf(v[i] - m) : 0.0f;
        v[i] = e; sum += e;
    }
#pragma unroll
    for (int off = 32; off; off >>= 1) sum += __shfl_xor(sum, off);
    float is = 1.0f / sum;
    unsigned int ow[8];
#pragma unroll
    for (int i = 0; i < 8; ++i)
        ow[i] = (unsigned)f2bf(v[2 * i] * is) | ((unsigned)f2bf(v[2 * i + 1] * is) << 16);
    ((uint4*)Srow)[lane * 2]     = make_uint4(ow[0], ow[1], ow[2], ow[3]);
    ((uint4*)Srow)[lane * 2 + 1] = make_uint4(ow[4], ow[5], ow[6], ow[7]);
}

// Fused hop: Pn = A @ Pprev (LDS-staged, double-buffered, one barrier/K-step,
// 1-deep register prefetch — 8 uint4 staging regs, no spill);
// [writeP: store Pn^T bf16]; filter GEMM from pre-transposed bf16 weights:
//   khop==1: Hacc = a0*(Xh@W0) + a1*(Pn@W1)   (bf16 store, init; hop-0 fused)
//   else:    Hacc += a_k*(Pn@Wk)              (bf16 RMW)
__global__ __launch_bounds__(256) void apf_mfma(const unsigned short* __restrict__ Abf,
                                                const unsigned short* __restrict__ Ptin,
                                                unsigned short* __restrict__ Ptout, int writeP,
                                                const unsigned short* __restrict__ Xn,
                                                const unsigned short* __restrict__ WtB,
                                                const float* __restrict__ alpha,
                                                unsigned short* __restrict__ HaccB, int khop) {
    __shared__ unsigned short A_lds[2][64 * LDA];
    __shared__ unsigned short P_lds[2][64 * LDA];
    __shared__ unsigned short PnL[64 * LDW];   // dedicated: no aliasing (r10 lesson)
    int tid = threadIdx.x, lane = tid & 63, w = tid >> 6;
    int bh = blockIdx.y, b = bh >> 3, h = bh & 7;
    int i0 = blockIdx.x << 6;
    const unsigned short* Ag = Abf + ((size_t)bh * Nq + i0) * Nq;   // [n][j]
    const unsigned short* Pg = Ptin + (size_t)bh * DHq * Nq;        // [d][n]
    int r0 = tid >> 4, oo = (tid & 15) << 3;

    uint4 ra[4], rp[4];
#pragma unroll
    for (int u = 0; u < 4; ++u) {
        ra[u] = *(const uint4*)&Ag[(size_t)(r0 + (u << 4)) * Nq + oo];
        rp[u] = *(const uint4*)&Pg[(size_t)(r0 + (u << 4)) * Nq + oo];
    }
#pragma unroll
    for (int u = 0; u < 4; ++u) {
        *(uint4*)&A_lds[0][(r0 + (u << 4)) * LDA + oo] = ra[u];
        *(uint4*)&P_lds[0][(r0 + (u << 4)) * LDA + oo] = rp[u];
    }
    __syncthreads();

    f32x4 acc[4] = {fzero(), fzero(), fzero(), fzero()};
    int brow = lane & 15, g = lane >> 4, ko = g << 3;
    int cur = 0;

    for (int kt = 0; kt < 8; ++kt) {
        if (kt < 7) {  // prefetch next slice into regs; hides under MFMAs
            int j = (kt + 1) << 7;
#pragma unroll
            for (int u = 0; u < 4; ++u) {
                ra[u] = *(const uint4*)&Ag[(size_t)(r0 + (u << 4)) * Nq + j + oo];
                rp[u] = *(const uint4*)&Pg[(size_t)(r0 + (u << 4)) * Nq + j + oo];
            }
        }
        const unsigned short* Afr = &A_lds[cur][((w << 4) + brow) * LDA + ko];
#pragma unroll
        for (int ks = 0; ks < 4; ++ks) {
            bf16x8 af = *(const bf16x8*)(Afr + (ks << 5));
#pragma unroll
            for (int nt = 0; nt < 4; ++nt) {
                bf16x8 bfv = *(const bf16x8*)&P_lds[cur][((nt << 4) + brow) * LDA + (ks << 5) + ko];
                acc[nt] = __builtin_amdgcn_mfma_f32_16x16x32_bf16(af, bfv, acc[nt], 0, 0, 0);
            }
        }
        if (kt < 7) {  // write other buffer: no WAR hazard, one barrier
#pragma unroll
            for (int u = 0; u < 4; ++u) {
                *(uint4*)&A_lds[cur ^ 1][(r0 + (u << 4)) * LDA + oo] = ra[u];
                *(uint4*)&P_lds[cur ^ 1][(r0 + (u << 4)) * LDA + oo] = rp[u];
            }
        }
        __syncthreads();
        cur ^= 1;
    }

    // acc: Pn[row=(w<<4)+(g<<2)+r][col=(nt<<4)+brow]
    int nrow = (w << 4) + (g << 2);
    int dcol = brow;
    if (writeP) {
#pragma unroll
        for (int nt = 0; nt < 4; ++nt) {
            uint2 pk = make_uint2(
                (unsigned)f2bf(acc[nt][0]) | ((unsigned)f2bf(acc[nt][1]) << 16),
                (unsigned)f2bf(acc[nt][2]) | ((unsigned)f2bf(acc[nt][3]) << 16));
            *(uint2*)&Ptout[(size_t)bh * DHq * Nq + (size_t)((nt << 4) + dcol) * Nq + i0 + nrow] = pk;
        }
    }
    // Pn -> A-frag layout [n][d] in dedicated LDS; barrier before reads.
#pragma unroll
    for (int nt = 0; nt < 4; ++nt)
#pragma unroll
        for (int r = 0; r < 4; ++r)
            PnL[(nrow + r) * LDW + (nt << 4) + dcol] = f2bf(acc[nt][r]);
    __syncthreads();

    // filter GEMM(s), K=64; W fragments direct from pre-transposed bf16 (tiny, L2-hot)
    const unsigned short* Wk = WtB + (size_t)(h * (KH + 1) + khop) * DHq * DHq;  // [e][d]
    f32x4 hacc[4] = {fzero(), fzero(), fzero(), fzero()};
    f32x4 hacc0[4] = {fzero(), fzero(), fzero(), fzero()};
#pragma unroll
    for (int ks = 0; ks < 2; ++ks) {
        bf16x8 pf = *(const bf16x8*)&PnL[((w << 4) + brow) * LDW + (ks << 5) + ko];
#pragma unroll
        for (int nt = 0; nt < 4; ++nt) {
            bf16x8 wf = *(const bf16x8*)&Wk[(size_t)((nt << 4) + brow) * DHq + (ks << 5) + ko];
            hacc[nt] = __builtin_amdgcn_mfma_f32_16x16x32_bf16(pf, wf, hacc[nt], 0, 0, 0);
        }
    }
    if (khop == 1) {  // fused hop-0: Xh @ W0
        const unsigned short* W0 = WtB + (size_t)(h * (KH + 1)) * DHq * DHq;
        const unsigned short* Xb = Xn + ((size_t)bh * Nq + i0) * DHq;
        int arow = (w << 4) + brow;
#pragma unroll
        for (int ks = 0; ks < 2; ++ks) {
            bf16x8 xf = *(const bf16x8*)&Xb[(size_t)arow * DHq + (ks << 5) + ko];
#pragma unroll
            for (int nt = 0; nt < 4; ++nt) {
                bf16x8 wf = *(const bf16x8*)&W0[(size_t)((nt << 4) + brow) * DHq + (ks << 5) + ko];
                hacc0[nt] = __builtin_amdgcn_mfma_f32_16x16x32_bf16(xf, wf, hacc0[nt], 0, 0, 0);
            }
        }
    }
    float av = alpha[h * (KH + 1) + khop];
    unsigned short* Ho = HaccB + ((size_t)b * Nq + i0 + nrow) * Dq + h * DHq;
    if (khop == 1) {
        float a0 = alpha[h * (KH + 1)];
#pragma unroll
        for (int nt = 0; nt < 4; ++nt)
#pragma unroll
            for (int r = 0; r < 4; ++r)
                Ho[(size_t)r * Dq + (nt << 4) + brow] = f2bf(a0 * hacc0[nt][r] + av * hacc[nt][r]);
    } else {
#pragma unroll
        for (int nt = 0; nt < 4; ++nt)
#pragma unroll
            for (int r = 0; r < 4; ++r) {
                unsigned short* p = Ho + (size_t)r * Dq + (nt << 4) + brow;
                *p = f2bf(bf2f(*p) + av * hacc[nt][r]);
            }
    }
}

// out = Hacc @ W_proj^T + b  (bf16 staged through LDS, f32 out)
__global__ __launch_bounds__(256) void proj_mfma(const unsigned short* __restrict__ HaccB,
                                                 const unsigned short* __restrict__ WpB,
                                                 const float* __restrict__ bp,
                                                 float* __restrict__ out) {
    __shared__ unsigned short Hl[64 * LDA], Wl[64 * LDA];
    int tid = threadIdx.x, lane = tid & 63, w = tid >> 6;
    int i0 = blockIdx.y << 6, j0 = blockIdx.x << 6;
    int brow = lane & 15, ko = (lane >> 4) << 3;
    f32x4 acc[4] = {fzero(), fzero(), fzero(), fzero()};
    for (int kt = 0; kt < 4; ++kt) {
#pragma unroll
        for (int u = 0; u < 4; ++u) {
            int idx = tid + (u << 8);
            int r = idx >> 4, c8 = (idx & 15) << 3;
            *(uint4*)&Hl[r * LDA + c8] = *(const uint4*)&HaccB[(size_t)(i0 + r) * Dq + (kt << 7) + c8];
            *(uint4*)&Wl[r * LDA + c8] = *(const uint4*)&WpB[(size_t)(j0 + r) * Dq + (kt << 7) + c8];
        }
        __syncthreads();
        const unsigned short* Afr = &Hl[((w << 4) + brow) * LDA + ko];
#pragma unroll
        for (int ks = 0; ks < 4; ++ks) {
            bf16x8 af = *(const bf16x8*)(Afr + (ks << 5));
#pragma unroll
            for (int nt = 0; nt < 4; ++nt) {
                bf16x8 bfv = *(const bf16x8*)&Wl[((nt << 4) + brow) * LDA + (ks << 5) + ko];
                acc[nt] = __builtin_amdgcn_mfma_f32_16x16x32_bf16(af, bfv, acc[nt], 0, 0, 0);
            }
        }
        __syncthreads();
    }
    int nrow = (w << 4) + ((lane >> 4) << 2);
#pragma unroll
    for (int nt = 0; nt < 4; ++nt) {
        float bb = bp[j0 + (nt << 4) + brow];
#pragma unroll
        for (int r = 0; r < 4; ++r)
            out[(size_t)(i0 + nrow + r) * Dq + j0 + (nt << 4) + brow] = acc[nt][r] + bb;
    }
}

// ---------------- launch ----------------

extern "C" void kernel_launch(void* const* d_in, const int* in_sizes, int n_in,
                              void* d_out, int out_size, void* d_ws, size_t ws_size,
                              hipStream_t stream) {
    (void)in_sizes; (void)n_in; (void)out_size; (void)ws_size;
    const float* X           = (const float*)d_in[0];
    const float* temperature = (const float*)d_in[1];
    const float* W_filt      = (const float*)d_in[2];
    const float* alpha       = (const float*)d_in[3];
    const float* W_proj      = (const float*)d_in[4];
    const float* b_proj      = (const float*)d_in[5];
    const int*   layer_idx   = (const int*)d_in[6];
    const int*   Lp          = (const int*)d_in[7];
    float* out = (float*)d_out;

    unsigned short* Abf  = (unsigned short*)d_ws;                   // S/A in place, 64 MiB
    unsigned short* Xn   = Abf  + (size_t)NBH * Nq * Nq;            // [32][1024][64]
    unsigned short* Xt   = Xn   + (size_t)NBH * Nq * DHq;           // [32][64][1024]
    unsigned short* Pt1  = Xt   + (size_t)NBH * DHq * Nq;           // [32][64][1024]
    unsigned short* Pt2  = Pt1  + (size_t)NBH * DHq * Nq;           // [32][64][1024]
    unsigned short* Hacc = Pt2  + (size_t)NBH * DHq * Nq;           // [4][1024][512] bf16
    unsigned short* WtB  = Hacc + (size_t)4 * Nq * Dq;              // [32][64][64]
    unsigned short* WpB  = WtB  + (size_t)NBH * DHq * DHq;          // [512][512]

    dim3 blk(256);
    xcast_kernel<<<dim3(16, 33), blk, 0, stream>>>(X, Xn, Xt, W_filt, W_proj, WtB, WpB);
    score_mfma<<<dim3(16, 16, 32), blk, 0, stream>>>(Xn, temperature, Abf);
    topk_softmax_kernel<<<dim3(NBH * Nq / 4), blk, 0, stream>>>(Abf, layer_idx, Lp);

    // hop 1 (+ fused hop 0): Pn = A @ Xh (Pprev^T = Xt); write Pt1
    apf_mfma<<<dim3(16, 32), blk, 0, stream>>>(Abf, Xt, Pt1, 1, Xn, WtB, alpha, Hacc, 1);
    // hop 2
    apf_mfma<<<dim3(16, 32), blk, 0, stream>>>(Abf, Pt1, Pt2, 1, Xn, WtB, alpha, Hacc, 2);
    // hop 3 (no P write)
    apf_mfma<<<dim3(16, 32), blk, 0, stream>>>(Abf, Pt2, nullptr, 0, Xn, WtB, alpha, Hacc, 3);

    proj_mfma<<<dim3(8, 64), blk, 0, stream>>>(Hacc, WpB, b_proj, out);
}